// Round 2
// baseline (136.804 us; speedup 1.0000x reference)
//
#include <hip/hip_runtime.h>
#include <math.h>

#define K_ 32
#define D_ 8
#define NF 48          // 36 quad + 8 lin + 1 const + 3 pad features
#define NTHREADS 256
#define NBLOCKS 1024
#define TPW 4          // tiles per wave, fully unrolled

typedef _Float16 half8 __attribute__((ext_vector_type(8)));
typedef float f32x16 __attribute__((ext_vector_type(16)));

// ---------------------------------------------------------------------------
// Round-12: per-lane prep, zero communication.
// Round-11 post-mortem: (a) separate 1-wave prep kernel cost ~18 us serial
// (launch + uncoalesced loads + dependency chains); (b) per-s-block feature
// rebuild (yb[16] under range guards) defeated scalarization -> PromoteAlloca
// put it in LDS (LDS_Block_Size=16384 with no __shared__!), 1.38e7 bank-
// conflict cycles, kernel 46.6 us with all pipes idle.
// Fix: the MFMA A-fragment of lane l is exactly V[k=l&31][16s+8h+j], h=l>>5.
// So EACH LANE computes its own k's prep (Cholesky inverse, A2, b, q, logdet,
// pi-lse) redundantly -- ~500 fully-unrolled register-resident VALU ops that
// OVERLAP the x-load HBM latency. No LDS, no barrier, no second kernel.
// B-operand features revert to round-10's proven full-Y[48] register pattern.
//
// Math (unchanged): maha = x^T A x - 2 b^T x + mu^T b with A = L^-T L^-1,
// b = A mu. In log2 domain (alpha = 0.5*log2e):
//   W2[n][k] = sum_f V[k][f] * Y[n][f],  Y = [x_i x_j (j<=i), x_i, 1, pad]
//   out = ln2 * log2(sum_k exp2(W2))  -- W2 in (-80,-3), no max-subtract
// 3x v_mfma_f32_32x32x16_f16 per 32-sample tile; A-op = weights (M=K_),
// B-op = features (N=samples). C-layout: row=k=(reg&3)+8*(reg>>2)+4*(lane>>5),
// col=sample=lane&31 -> k-reduce = 16 exp2 + 15 adds in-lane + 1 shfl_xor(32).
// Grid covers tiles exactly: 1024 blk x 4 waves x 4 tiles = 16384 = N/32.
// ---------------------------------------------------------------------------
__global__ __launch_bounds__(NTHREADS, 4) void gmm_mfma(
    const float* __restrict__ x,
    const float* __restrict__ pi,
    const float* __restrict__ means,
    const float* __restrict__ chol,
    float* __restrict__ out)
{
    const int tid  = threadIdx.x;
    const int lane = tid & 63;
    const int m    = lane & 31;   // sample col within tile; also this lane's k
    const bool h1  = lane >= 32;
    const int k    = m;

    const int w  = blockIdx.x * (NTHREADS / 64) + (tid >> 6);
    const int t0 = w * TPW;
    const float4* xp = (const float4*)x;
    const float LN2 = 0.69314718055994531f;

    // ---- issue first 2 tiles' x-loads; their latency hides under prep ----
    float xv[TPW][D_];
#pragma unroll
    for (int u = 0; u < 2; ++u) {
        const int n = (t0 + u) * 32 + m;
        float4 a = xp[2 * n], b2 = xp[2 * n + 1];
        xv[u][0] = a.x;  xv[u][1] = a.y;  xv[u][2] = a.z;  xv[u][3] = a.w;
        xv[u][4] = b2.x; xv[u][5] = b2.y; xv[u][6] = b2.z; xv[u][7] = b2.w;
    }

    // ---- per-lane prep for k = lane&31 (all register-resident) ----
    // pi logsumexp first (p[] dies before L/Ci peak)
    float lse, pik;
    {
        const float4* pp = (const float4*)pi;
        float p[K_];
#pragma unroll
        for (int t = 0; t < 8; ++t) {
            float4 a = pp[t];
            p[4 * t] = a.x; p[4 * t + 1] = a.y; p[4 * t + 2] = a.z; p[4 * t + 3] = a.w;
        }
        float mx = p[0];
#pragma unroll
        for (int t = 1; t < K_; ++t) mx = fmaxf(mx, p[t]);
        float se = 0.f;
#pragma unroll
        for (int t = 0; t < K_; ++t) se += __expf(p[t] - mx);
        lse = mx + __logf(se);
        pik = p[k];
    }

    float L[D_][D_];
    {
        const float4* cp = (const float4*)(chol + k * 64);
#pragma unroll
        for (int i = 0; i < D_; ++i) {
            float4 a = cp[2 * i];
            L[i][0] = a.x; L[i][1] = a.y; L[i][2] = a.z; L[i][3] = a.w;
            if (i >= 4) {
                float4 bq = cp[2 * i + 1];
                L[i][4] = bq.x; L[i][5] = bq.y; L[i][6] = bq.z; L[i][7] = bq.w;
            }
        }
    }

    float rd[D_];
#pragma unroll
    for (int i = 0; i < D_; ++i) rd[i] = 1.f / L[i][i];

    // Ci = L^{-1}; chol(LL^T + eps I) = L*sign, maha/logdet sign-invariant
    float Ci[D_][D_];
#pragma unroll
    for (int j = 0; j < D_; ++j) {
        Ci[j][j] = rd[j];
#pragma unroll
        for (int i = j + 1; i < D_; ++i) {
            float s = 0.f;
#pragma unroll
            for (int mm = j; mm < i; ++mm) s += L[i][mm] * Ci[mm][j];
            Ci[i][j] = -s * rd[i];
        }
    }

    float logdet = 0.f;
#pragma unroll
    for (int i = 0; i < D_; ++i) logdet += __logf(fabsf(L[i][i]));
    logdet *= 2.f;

    // A2 = Ci^T Ci (L dead, Ci dies as A2 completes)
    float A2[D_][D_];
#pragma unroll
    for (int i = 0; i < D_; ++i)
#pragma unroll
        for (int j = 0; j <= i; ++j) {
            float s = 0.f;
#pragma unroll
            for (int mm = i; mm < D_; ++mm) s += Ci[mm][i] * Ci[mm][j];
            A2[i][j] = s;
            A2[j][i] = s;
        }

    float b[D_], q = 0.f;
    {
        const float4* mp = (const float4*)(means + k * 8);
        float4 ma = mp[0], mb = mp[1];
        float mu[D_] = {ma.x, ma.y, ma.z, ma.w, mb.x, mb.y, mb.z, mb.w};
#pragma unroll
        for (int i = 0; i < D_; ++i) {
            float s = 0.f;
#pragma unroll
            for (int j = 0; j < D_; ++j) s += A2[i][j] * mu[j];
            b[i] = s;
            q += s * mu[i];
        }
    }

    const float LOG2PI = 1.8378770664093453f;
    const float LOG2E  = 1.4426950408889634f;
    const float ALPHA  = 0.72134752044448170f;  // 0.5 * log2e
    float cst2 = ((pik - lse) - 0.5f * (logdet + 8.f * LOG2PI)) * LOG2E;

    float V[NF];
    {
        int t = 0;
#pragma unroll
        for (int i = 0; i < D_; ++i)
#pragma unroll
            for (int j = 0; j <= i; ++j)
                V[t++] = (i == j) ? -ALPHA * A2[i][i] : -2.f * ALPHA * A2[i][j];
#pragma unroll
        for (int i = 0; i < D_; ++i) V[36 + i] = 2.f * ALPHA * b[i];
        V[44] = cst2 - ALPHA * q;
        V[45] = 0.f; V[46] = 0.f; V[47] = 0.f;
    }

    // A-operand fragments: lane l holds V[k=l&31][16s + 8*(l>>5) + j]
    half8 wf[3];
#pragma unroll
    for (int s = 0; s < 3; ++s)
#pragma unroll
        for (int j = 0; j < 8; ++j)
            wf[s][j] = (_Float16)(h1 ? V[16 * s + 8 + j] : V[16 * s + j]);

    // ---- remaining tiles' x-loads; latency hides under tile-0 compute ----
#pragma unroll
    for (int u = 2; u < TPW; ++u) {
        const int n = (t0 + u) * 32 + m;
        float4 a = xp[2 * n], b2 = xp[2 * n + 1];
        xv[u][0] = a.x;  xv[u][1] = a.y;  xv[u][2] = a.z;  xv[u][3] = a.w;
        xv[u][4] = b2.x; xv[u][5] = b2.y; xv[u][6] = b2.z; xv[u][7] = b2.w;
    }

#pragma unroll
    for (int u = 0; u < TPW; ++u) {
        // full Y[48] with constant indices -- register-resident (round-10 proven)
        float Y[NF];
        {
            int t = 0;
#pragma unroll
            for (int i = 0; i < D_; ++i)
#pragma unroll
                for (int j = 0; j <= i; ++j) Y[t++] = xv[u][i] * xv[u][j];
#pragma unroll
            for (int i = 0; i < D_; ++i) Y[36 + i] = xv[u][i];
            Y[44] = 1.f; Y[45] = 0.f; Y[46] = 0.f; Y[47] = 0.f;
        }

        f32x16 acc;
#pragma unroll
        for (int r = 0; r < 16; ++r) acc[r] = 0.f;

#pragma unroll
        for (int s = 0; s < 3; ++s) {
            half8 bf;
#pragma unroll
            for (int j = 0; j < 8; ++j) {
                float v = h1 ? Y[16 * s + 8 + j] : Y[16 * s + j];
                bf[j] = (_Float16)v;
            }
            acc = __builtin_amdgcn_mfma_f32_32x32x16_f16(wf[s], bf, acc, 0, 0, 0);
        }

        float tot = 0.f;
#pragma unroll
        for (int r = 0; r < 16; ++r) tot += exp2f(acc[r]);
        tot += __shfl_xor(tot, 32, 64);
        float res = log2f(tot) * LN2;
        if (!h1) out[(t0 + u) * 32 + m] = res;  // coalesced 128B store
    }
}

extern "C" void kernel_launch(void* const* d_in, const int* in_sizes, int n_in,
                              void* d_out, int out_size, void* d_ws, size_t ws_size,
                              hipStream_t stream) {
    const float* x     = (const float*)d_in[0];
    const float* pi    = (const float*)d_in[1];
    const float* means = (const float*)d_in[2];
    const float* chol  = (const float*)d_in[3];
    float* out = (float*)d_out;
    (void)in_sizes; (void)n_in; (void)out_size; (void)d_ws; (void)ws_size;

    gmm_mfma<<<NBLOCKS, NTHREADS, 0, stream>>>(x, pi, means, chol, out);
}

// Round 3
// 75.728 us; speedup vs baseline: 1.8065x; 1.8065x over previous
//
#include <hip/hip_runtime.h>
#include <math.h>

#define K_ 32
#define D_ 8
#define NF 48          // 36 quad + 8 lin + 1 const + 3 pad features
#define NTHREADS 256
#define NBLOCKS 1024
#define TPW 4          // tiles per wave, fully unrolled, loads hoisted

typedef _Float16 half8 __attribute__((ext_vector_type(8)));
typedef float f32x16 __attribute__((ext_vector_type(16)));

// ---------------------------------------------------------------------------
// Round-13: round-0 topology restored (prep in 32 lanes of wave 0 -> f16 LDS
// table -> barrier -> MFMA loop; proven dur 75 / kernel <=31us), with three
// register-pressure cuts aimed at the whole-kernel VGPR allocation that the
// prep path's ~240 live floats was driving:
//   1. in-place TRTRI: Ci overwrites L column-by-column (no separate Ci[64]);
//      logdet recovered from rd[] since the diagonal gets overwritten.
//   2. A2 overwrites Ci row-by-row via an 8-float row temp (no separate
//      A2[64]); only lower-triangular 36 slots stay live.
//   3. waves 1-3 issue x-loads BEFORE the barrier (latency hides under
//      wave 0's prep); wave 0 loads after. Prep peak excludes xv[32].
// Round-11/12 lessons honored: no separate prep kernel (+18us launch/serial),
// no per-lane redundant prep (scratch blowup: 217MB WRITE_SIZE, VGPR=48),
// no range-guarded array writes (LDS-alloca trap), every private array index
// a compile-time constant, no runtime p[k] (pi[k] is a direct global load).
//
// Math (unchanged): maha = x^T A x - 2 b^T x + mu^T b with A = L^-T L^-1,
// b = A mu. In log2 domain (alpha = 0.5*log2e):
//   W2[n][k] = sum_f V[k][f] * Y[n][f],  Y = [x_i x_j (j<=i), x_i, 1, pad]
//   out = ln2 * log2(sum_k exp2(W2))  -- W2 in (-80,-3), no max-subtract
// 3x v_mfma_f32_32x32x16_f16 per 32-sample tile; A-op = weights (M=K_),
// B-op = features (N=samples). C-layout: row=k=(reg&3)+8*(reg>>2)+4*(lane>>5),
// col=sample=lane&31 -> k-reduce = 16 exp2 + 15 adds in-lane + 1 shfl_xor(32).
// Grid covers tiles exactly: 1024 blk x 4 waves x 4 tiles = 16384 = N/32.
// ---------------------------------------------------------------------------
__global__ __launch_bounds__(NTHREADS) void gmm_mfma(
    const float* __restrict__ x,
    const float* __restrict__ pi,
    const float* __restrict__ means,
    const float* __restrict__ chol,
    float* __restrict__ out)
{
    // A-operand fragments (weights), f16: lane l holds A[m=l&31][kk=8*(l>>5)+j]
    __shared__ __align__(16) _Float16 ldsA[3][64][8];

    const int tid  = threadIdx.x;
    const int lane = tid & 63;
    const int m    = lane & 31;
    const bool h1  = lane >= 32;

    const int w  = blockIdx.x * (NTHREADS / 64) + (tid >> 6);
    const int t0 = w * TPW;
    const float4* xp = (const float4*)x;

    // ---- waves 1-3: issue all x-loads now; latency hides under wave0 prep ----
    float xv[TPW][D_];
    if (tid >= 64) {
#pragma unroll
        for (int u = 0; u < TPW; ++u) {
            const int n = (t0 + u) * 32 + m;
            float4 a = xp[2 * n], b2 = xp[2 * n + 1];
            xv[u][0] = a.x;  xv[u][1] = a.y;  xv[u][2] = a.z;  xv[u][3] = a.w;
            xv[u][4] = b2.x; xv[u][5] = b2.y; xv[u][6] = b2.z; xv[u][7] = b2.w;
        }
    }

    if (tid < K_) {
        const int k = tid;

        // M starts as L (lower triangle), becomes Ci in-place, then A2 in-place.
        float M[D_][D_];
        {
            const float4* cp = (const float4*)(chol + k * 64);
#pragma unroll
            for (int i = 0; i < D_; ++i) {
                float4 a = cp[2 * i];
                M[i][0] = a.x; M[i][1] = a.y; M[i][2] = a.z; M[i][3] = a.w;
                if (i >= 4) {
                    float4 bq = cp[2 * i + 1];
                    M[i][4] = bq.x; M[i][5] = bq.y; M[i][6] = bq.z; M[i][7] = bq.w;
                }
            }
        }

        float rd[D_];
#pragma unroll
        for (int i = 0; i < D_; ++i) rd[i] = 1.f / M[i][i];

        // logdet from rd: log|L_ii| = -log|rd_i|  (diag gets overwritten below)
        float logdet = 0.f;
#pragma unroll
        for (int i = 0; i < D_; ++i) logdet += __logf(fabsf(rd[i]));
        logdet *= -2.f;

        // In-place TRTRI: column j overwritten with Ci[:,j].
        // Ci[i][j] = -rd[i] * sum_{mm=j}^{i-1} L[i][mm] * Ci[mm][j], Ci[j][j]=rd[j].
        // Reads: M[i][mm] for mm in [j,i) -- column j read-before-write, columns
        // (j,i) still original (processed later); M[mm][j] already Ci. No alias.
#pragma unroll
        for (int j = 0; j < D_; ++j) {
            M[j][j] = rd[j];
#pragma unroll
            for (int i = j + 1; i < D_; ++i) {
                float s = 0.f;
#pragma unroll
                for (int mm = j; mm < i; ++mm) s += M[i][mm] * M[mm][j];
                M[i][j] = -s * rd[i];
            }
        }

        // In-place A2 = Ci^T Ci (lower): row i computed into temp (reads rows
        // >= i only, which are still Ci), then written over row i.
#pragma unroll
        for (int i = 0; i < D_; ++i) {
            float t[D_];
#pragma unroll
            for (int j = 0; j <= i; ++j) {
                float s = 0.f;
#pragma unroll
                for (int mm = i; mm < D_; ++mm) s += M[mm][i] * M[mm][j];
                t[j] = s;
            }
#pragma unroll
            for (int j = 0; j <= i; ++j) M[i][j] = t[j];
        }
        // Now M holds A2 lower triangle: A2[i][j] = M[i][j] for j<=i.

        float b[D_], q = 0.f;
        {
            const float4* mp = (const float4*)(means + k * 8);
            float4 ma = mp[0], mb = mp[1];
            float mu[D_] = {ma.x, ma.y, ma.z, ma.w, mb.x, mb.y, mb.z, mb.w};
#pragma unroll
            for (int i = 0; i < D_; ++i) {
                float s = 0.f;
#pragma unroll
                for (int j = 0; j <= i; ++j) s += M[i][j] * mu[j];
#pragma unroll
                for (int j = i + 1; j < D_; ++j) s += M[j][i] * mu[j];
                b[i] = s;
                q += s * mu[i];
            }
        }

        // pi logsumexp: uniform scalar loads, constant indices only
        float lse;
        {
            float mx = pi[0];
#pragma unroll
            for (int t = 1; t < K_; ++t) mx = fmaxf(mx, pi[t]);
            float se = 0.f;
#pragma unroll
            for (int t = 0; t < K_; ++t) se += __expf(pi[t] - mx);
            lse = mx + __logf(se);
        }

        const float LOG2PI = 1.8378770664093453f;
        const float LOG2E  = 1.4426950408889634f;
        const float ALPHA  = 0.72134752044448170f;  // 0.5 * log2e
        float cst2 = ((pi[k] - lse) - 0.5f * (logdet + 8.f * LOG2PI)) * LOG2E;

        float V[NF];
        {
            int t = 0;
#pragma unroll
            for (int i = 0; i < D_; ++i)
#pragma unroll
                for (int j = 0; j <= i; ++j)
                    V[t++] = (i == j) ? -ALPHA * M[i][i] : -2.f * ALPHA * M[i][j];
#pragma unroll
            for (int i = 0; i < D_; ++i) V[36 + i] = 2.f * ALPHA * b[i];
            V[44] = cst2 - ALPHA * q;
            V[45] = 0.f; V[46] = 0.f; V[47] = 0.f;
        }

        // f16 fragment table: one 16B LDS store per (s,h)
#pragma unroll
        for (int s = 0; s < 3; ++s)
#pragma unroll
            for (int h = 0; h < 2; ++h) {
                half8 hv;
#pragma unroll
                for (int j = 0; j < 8; ++j) hv[j] = (_Float16)V[16 * s + 8 * h + j];
                *(half8*)&ldsA[s][h * 32 + k][0] = hv;
            }
    }
    __syncthreads();

    // ---- wave 0: loads after barrier (prep path stayed lean) ----
    if (tid < 64) {
#pragma unroll
        for (int u = 0; u < TPW; ++u) {
            const int n = (t0 + u) * 32 + m;
            float4 a = xp[2 * n], b2 = xp[2 * n + 1];
            xv[u][0] = a.x;  xv[u][1] = a.y;  xv[u][2] = a.z;  xv[u][3] = a.w;
            xv[u][4] = b2.x; xv[u][5] = b2.y; xv[u][6] = b2.z; xv[u][7] = b2.w;
        }
    }

    half8 wf[3];
#pragma unroll
    for (int s = 0; s < 3; ++s) wf[s] = *(const half8*)&ldsA[s][lane][0];

    const float LN2 = 0.69314718055994531f;

#pragma unroll
    for (int u = 0; u < TPW; ++u) {
        // full Y[48], constant indices -- register-resident (round-0 proven)
        float Y[NF];
        {
            int t = 0;
#pragma unroll
            for (int i = 0; i < D_; ++i)
#pragma unroll
                for (int j = 0; j <= i; ++j) Y[t++] = xv[u][i] * xv[u][j];
#pragma unroll
            for (int i = 0; i < D_; ++i) Y[36 + i] = xv[u][i];
            Y[44] = 1.f; Y[45] = 0.f; Y[46] = 0.f; Y[47] = 0.f;
        }

        f32x16 acc;
#pragma unroll
        for (int r = 0; r < 16; ++r) acc[r] = 0.f;

#pragma unroll
        for (int s = 0; s < 3; ++s) {
            half8 bf;
#pragma unroll
            for (int j = 0; j < 8; ++j) {
                float v = h1 ? Y[16 * s + 8 + j] : Y[16 * s + j];
                bf[j] = (_Float16)v;
            }
            acc = __builtin_amdgcn_mfma_f32_32x32x16_f16(wf[s], bf, acc, 0, 0, 0);
        }

        float tot = 0.f;
#pragma unroll
        for (int r = 0; r < 16; ++r) tot += exp2f(acc[r]);
        tot += __shfl_xor(tot, 32, 64);
        float res = log2f(tot) * LN2;
        if (!h1) out[(t0 + u) * 32 + m] = res;  // coalesced 128B store
    }
}

extern "C" void kernel_launch(void* const* d_in, const int* in_sizes, int n_in,
                              void* d_out, int out_size, void* d_ws, size_t ws_size,
                              hipStream_t stream) {
    const float* x     = (const float*)d_in[0];
    const float* pi    = (const float*)d_in[1];
    const float* means = (const float*)d_in[2];
    const float* chol  = (const float*)d_in[3];
    float* out = (float*)d_out;
    (void)in_sizes; (void)n_in; (void)out_size; (void)d_ws; (void)ws_size;

    gmm_mfma<<<NBLOCKS, NTHREADS, 0, stream>>>(x, pi, means, chol, out);
}

// Round 4
// 74.787 us; speedup vs baseline: 1.8292x; 1.0126x over previous
//
#include <hip/hip_runtime.h>
#include <math.h>

#define K_ 32
#define D_ 8
#define NF 48          // 36 quad + 8 lin + 1 const + 3 pad features
#define NTHREADS 256
#define NBLOCKS 1024
#define TPW 4          // tiles per wave, fully unrolled, loads hoisted

typedef _Float16 half8 __attribute__((ext_vector_type(8)));
typedef float f32x16 __attribute__((ext_vector_type(16)));

// ---------------------------------------------------------------------------
// Round-14: split topology (round-1) with proven components (round-0/3).
// Accounting across rounds 1-3 (common reset overhead R~17us): the round-1
// split's serial cost was only ~1.6us -- its 46us hot kernel was the yb[16]
// LDS-alloca bug, not the split. Current fused kernel ~15us vs ~5us roofline;
// the gap is the in-kernel prep: prep path's ~110 live floats drive whole-
// kernel VGPR (occupancy), and every block pays a serial half-wave prep with
// 3 waves parked at the barrier.
// This version: gmm_prep (1 wave, round-3's lean in-place math VERBATIM)
// writes the 3KB f16 A-fragment table to workspace; gmm_mfma keeps the
// round-0-proven full-Y[48] register loop and loads wf[3] from the table
// (L2-resident, 3KB shared by all 4096 waves). Hot kernel: no prep, no LDS,
// no barrier. Lessons honored: constant indices everywhere (no LDS-alloca /
// scratch traps), no per-lane redundant prep, main-loop numerics verbatim.
//
// Math (unchanged): maha = x^T A x - 2 b^T x + mu^T b with A = L^-T L^-1,
// b = A mu. In log2 domain (alpha = 0.5*log2e):
//   W2[n][k] = sum_f V[k][f] * Y[n][f],  Y = [x_i x_j (j<=i), x_i, 1, pad]
//   out = ln2 * log2(sum_k exp2(W2))  -- W2 in (-80,-3), no max-subtract
// 3x v_mfma_f32_32x32x16_f16 per 32-sample tile; A-op = weights (M=K_),
// B-op = features (N=samples). C-layout: row=k=(reg&3)+8*(reg>>2)+4*(lane>>5),
// col=sample=lane&31 -> k-reduce = 16 exp2 + 15 adds in-lane + 1 shfl_xor(32).
// Grid covers tiles exactly: 1024 blk x 4 waves x 4 tiles = 16384 = N/32.
// ---------------------------------------------------------------------------

__global__ void gmm_prep(
    const float* __restrict__ pi,
    const float* __restrict__ means,
    const float* __restrict__ chol,
    _Float16* __restrict__ wsV)
{
    const int k = threadIdx.x;
    if (k >= K_) return;

    // M starts as L (lower triangle), becomes Ci in-place, then A2 in-place.
    float M[D_][D_];
    {
        const float4* cp = (const float4*)(chol + k * 64);
#pragma unroll
        for (int i = 0; i < D_; ++i) {
            float4 a = cp[2 * i];
            M[i][0] = a.x; M[i][1] = a.y; M[i][2] = a.z; M[i][3] = a.w;
            if (i >= 4) {
                float4 bq = cp[2 * i + 1];
                M[i][4] = bq.x; M[i][5] = bq.y; M[i][6] = bq.z; M[i][7] = bq.w;
            }
        }
    }

    float rd[D_];
#pragma unroll
    for (int i = 0; i < D_; ++i) rd[i] = 1.f / M[i][i];

    // logdet from rd: log|L_ii| = -log|rd_i|  (diag gets overwritten below)
    float logdet = 0.f;
#pragma unroll
    for (int i = 0; i < D_; ++i) logdet += __logf(fabsf(rd[i]));
    logdet *= -2.f;

    // In-place TRTRI: column j overwritten with Ci[:,j].
#pragma unroll
    for (int j = 0; j < D_; ++j) {
        M[j][j] = rd[j];
#pragma unroll
        for (int i = j + 1; i < D_; ++i) {
            float s = 0.f;
#pragma unroll
            for (int mm = j; mm < i; ++mm) s += M[i][mm] * M[mm][j];
            M[i][j] = -s * rd[i];
        }
    }

    // In-place A2 = Ci^T Ci (lower): row i from temp (reads rows >= i only).
#pragma unroll
    for (int i = 0; i < D_; ++i) {
        float t[D_];
#pragma unroll
        for (int j = 0; j <= i; ++j) {
            float s = 0.f;
#pragma unroll
            for (int mm = i; mm < D_; ++mm) s += M[mm][i] * M[mm][j];
            t[j] = s;
        }
#pragma unroll
        for (int j = 0; j <= i; ++j) M[i][j] = t[j];
    }
    // M holds A2 lower triangle.

    float b[D_], q = 0.f;
    {
        const float4* mp = (const float4*)(means + k * 8);
        float4 ma = mp[0], mb = mp[1];
        float mu[D_] = {ma.x, ma.y, ma.z, ma.w, mb.x, mb.y, mb.z, mb.w};
#pragma unroll
        for (int i = 0; i < D_; ++i) {
            float s = 0.f;
#pragma unroll
            for (int j = 0; j <= i; ++j) s += M[i][j] * mu[j];
#pragma unroll
            for (int j = i + 1; j < D_; ++j) s += M[j][i] * mu[j];
            b[i] = s;
            q += s * mu[i];
        }
    }

    // pi logsumexp: uniform scalar loads, constant indices only
    float lse;
    {
        float mx = pi[0];
#pragma unroll
        for (int t = 1; t < K_; ++t) mx = fmaxf(mx, pi[t]);
        float se = 0.f;
#pragma unroll
        for (int t = 0; t < K_; ++t) se += __expf(pi[t] - mx);
        lse = mx + __logf(se);
    }

    const float LOG2PI = 1.8378770664093453f;
    const float LOG2E  = 1.4426950408889634f;
    const float ALPHA  = 0.72134752044448170f;  // 0.5 * log2e
    float cst2 = ((pi[k] - lse) - 0.5f * (logdet + 8.f * LOG2PI)) * LOG2E;

    float V[NF];
    {
        int t = 0;
#pragma unroll
        for (int i = 0; i < D_; ++i)
#pragma unroll
            for (int j = 0; j <= i; ++j)
                V[t++] = (i == j) ? -ALPHA * M[i][i] : -2.f * ALPHA * M[i][j];
#pragma unroll
        for (int i = 0; i < D_; ++i) V[36 + i] = 2.f * ALPHA * b[i];
        V[44] = cst2 - ALPHA * q;
        V[45] = 0.f; V[46] = 0.f; V[47] = 0.f;
    }

    // fragment table: hot-kernel lane l reads wsV[s][l][0..7], l = h*32 + k
#pragma unroll
    for (int s = 0; s < 3; ++s)
#pragma unroll
        for (int h = 0; h < 2; ++h) {
            half8 hv;
#pragma unroll
            for (int j = 0; j < 8; ++j) hv[j] = (_Float16)V[16 * s + 8 * h + j];
            *(half8*)&wsV[(s * 64 + h * 32 + k) * 8] = hv;
        }
}

__global__ __launch_bounds__(NTHREADS) void gmm_mfma(
    const float* __restrict__ x,
    const _Float16* __restrict__ wsV,
    float* __restrict__ out)
{
    const int tid  = threadIdx.x;
    const int lane = tid & 63;
    const int m    = lane & 31;
    const bool h1  = lane >= 32;

    const int w  = blockIdx.x * (NTHREADS / 64) + (tid >> 6);
    const int t0 = w * TPW;
    const float4* xp = (const float4*)x;
    const float LN2 = 0.69314718055994531f;

    // ---- all x-loads issued first ----
    float xv[TPW][D_];
#pragma unroll
    for (int u = 0; u < TPW; ++u) {
        const int n = (t0 + u) * 32 + m;
        float4 a = xp[2 * n], b2 = xp[2 * n + 1];
        xv[u][0] = a.x;  xv[u][1] = a.y;  xv[u][2] = a.z;  xv[u][3] = a.w;
        xv[u][4] = b2.x; xv[u][5] = b2.y; xv[u][6] = b2.z; xv[u][7] = b2.w;
    }

    // A-fragments from the 3KB L2-resident table (latency hides under x-loads)
    const half8* wp = (const half8*)wsV;
    half8 wf[3];
#pragma unroll
    for (int s = 0; s < 3; ++s) wf[s] = wp[s * 64 + lane];

#pragma unroll
    for (int u = 0; u < TPW; ++u) {
        // full Y[48], constant indices -- register-resident (round-0 proven)
        float Y[NF];
        {
            int t = 0;
#pragma unroll
            for (int i = 0; i < D_; ++i)
#pragma unroll
                for (int j = 0; j <= i; ++j) Y[t++] = xv[u][i] * xv[u][j];
#pragma unroll
            for (int i = 0; i < D_; ++i) Y[36 + i] = xv[u][i];
            Y[44] = 1.f; Y[45] = 0.f; Y[46] = 0.f; Y[47] = 0.f;
        }

        f32x16 acc;
#pragma unroll
        for (int r = 0; r < 16; ++r) acc[r] = 0.f;

#pragma unroll
        for (int s = 0; s < 3; ++s) {
            half8 bf;
#pragma unroll
            for (int j = 0; j < 8; ++j) {
                float v = h1 ? Y[16 * s + 8 + j] : Y[16 * s + j];
                bf[j] = (_Float16)v;
            }
            acc = __builtin_amdgcn_mfma_f32_32x32x16_f16(wf[s], bf, acc, 0, 0, 0);
        }

        float tot = 0.f;
#pragma unroll
        for (int r = 0; r < 16; ++r) tot += exp2f(acc[r]);
        tot += __shfl_xor(tot, 32, 64);
        float res = log2f(tot) * LN2;
        if (!h1) out[(t0 + u) * 32 + m] = res;  // coalesced 128B store
    }
}

extern "C" void kernel_launch(void* const* d_in, const int* in_sizes, int n_in,
                              void* d_out, int out_size, void* d_ws, size_t ws_size,
                              hipStream_t stream) {
    const float* x     = (const float*)d_in[0];
    const float* pi    = (const float*)d_in[1];
    const float* means = (const float*)d_in[2];
    const float* chol  = (const float*)d_in[3];
    float* out = (float*)d_out;
    _Float16* wsV = (_Float16*)d_ws;
    (void)in_sizes; (void)n_in; (void)out_size; (void)ws_size;

    gmm_prep<<<1, 64, 0, stream>>>(pi, means, chol, wsV);
    gmm_mfma<<<NBLOCKS, NTHREADS, 0, stream>>>(x, wsV, out);
}

// Round 6
// 74.670 us; speedup vs baseline: 1.8321x; 1.0016x over previous
//
#include <hip/hip_runtime.h>
#include <math.h>

#define K_ 32
#define D_ 8
#define NF 80          // 64 full-matrix quad + 8 lin + 1 const + 7 pad
#define NS 5           // NF/16 MFMA k-blocks
#define NTHREADS 256
#define NBLOCKS 1024
#define TPW 4          // tiles per wave, fully unrolled, loads hoisted

typedef _Float16 half8 __attribute__((ext_vector_type(8)));
typedef __fp16 fp16x2 __attribute__((ext_vector_type(2)));
typedef float f32x16 __attribute__((ext_vector_type(16)));

// ---------------------------------------------------------------------------
// Round-15b: row-structured full-matrix features (VALU cut in the hot loop).
// (15a failed to compile: cvt_pkrtz returns __fp16x2 not _Float16x2; fixed
// with an __fp16-typed receiver + element casts, zero codegen change.)
// Accounting r0-r4: fixed harness ~60.5us (fill 43 + ~17.5 misc); prep+gmm
// ~14.5us, all topologies equal -> hot loop itself ~12-13us, dominated by
// per-tile B-fragment build (36 mul + 24 cndmask select + scalar cvts) and
// 16 acc-init movs. Fix: use the FULL product matrix (V holds A2[i][j]
// un-doubled; sum_ij A2_ij x_i x_j == maha quad term). Feature f=8i+j, so
// fragment slice (s,h) = row i=2s+h: per lane bc=x_{2s+h} (1 cndmask) times
// x-vector = 8 mul + 4 v_cvt_pkrtz packs. s=4 block: h0 = linear features
// (packed xh), h1 = (1,0,...) const reg. 5 MFMAs/tile (was 3) -- MFMA is
// cheap; build drops 84 -> ~56 issue slots/tile. acc init removed via
// loop-invariant zero C-operand on the first MFMA.
// pkrtz = RTZ rounding (vs RNE casts): same f16-quantization error class.
//
// Math: W2[n][k] = sum_f V[k][f] Y[n][f]; Y = [x_i x_j (all i,j), x, 1, pad]
//   V[8i+j] = -alpha*A2[i][j]; V[64+j] = 2*alpha*b[j]; V[72] = cst2-alpha*q
//   out = ln2 * log2(sum_k exp2(W2))   (W2 in (-80,-3), no max-subtract)
// C-layout (32x32x16): row=k=(reg&3)+8*(reg>>2)+4*(lane>>5), col=lane&31
// -> k-reduce = 16 exp2 + add tree in-lane + 1 shfl_xor(32).
// Grid: 1024 blk x 4 waves x 4 tiles = 16384 tiles = N/32.
// ---------------------------------------------------------------------------

__global__ void gmm_prep(
    const float* __restrict__ pi,
    const float* __restrict__ means,
    const float* __restrict__ chol,
    _Float16* __restrict__ wsV)
{
    const int k = threadIdx.x;
    if (k >= K_) return;

    // M starts as L (lower triangle), becomes Ci in-place, then A2 in-place.
    float M[D_][D_];
    {
        const float4* cp = (const float4*)(chol + k * 64);
#pragma unroll
        for (int i = 0; i < D_; ++i) {
            float4 a = cp[2 * i];
            M[i][0] = a.x; M[i][1] = a.y; M[i][2] = a.z; M[i][3] = a.w;
            if (i >= 4) {
                float4 bq = cp[2 * i + 1];
                M[i][4] = bq.x; M[i][5] = bq.y; M[i][6] = bq.z; M[i][7] = bq.w;
            }
        }
    }

    float rd[D_];
#pragma unroll
    for (int i = 0; i < D_; ++i) rd[i] = 1.f / M[i][i];

    float logdet = 0.f;
#pragma unroll
    for (int i = 0; i < D_; ++i) logdet += __logf(fabsf(rd[i]));
    logdet *= -2.f;

    // In-place TRTRI: column j overwritten with Ci[:,j].
#pragma unroll
    for (int j = 0; j < D_; ++j) {
        M[j][j] = rd[j];
#pragma unroll
        for (int i = j + 1; i < D_; ++i) {
            float s = 0.f;
#pragma unroll
            for (int mm = j; mm < i; ++mm) s += M[i][mm] * M[mm][j];
            M[i][j] = -s * rd[i];
        }
    }

    // In-place A2 = Ci^T Ci (lower): row i from temp (reads rows >= i only).
#pragma unroll
    for (int i = 0; i < D_; ++i) {
        float t[D_];
#pragma unroll
        for (int j = 0; j <= i; ++j) {
            float s = 0.f;
#pragma unroll
            for (int mm = i; mm < D_; ++mm) s += M[mm][i] * M[mm][j];
            t[j] = s;
        }
#pragma unroll
        for (int j = 0; j <= i; ++j) M[i][j] = t[j];
    }
    // M holds A2 lower triangle.

    float b[D_], q = 0.f;
    {
        const float4* mp = (const float4*)(means + k * 8);
        float4 ma = mp[0], mb = mp[1];
        float mu[D_] = {ma.x, ma.y, ma.z, ma.w, mb.x, mb.y, mb.z, mb.w};
#pragma unroll
        for (int i = 0; i < D_; ++i) {
            float s = 0.f;
#pragma unroll
            for (int j = 0; j <= i; ++j) s += M[i][j] * mu[j];
#pragma unroll
            for (int j = i + 1; j < D_; ++j) s += M[j][i] * mu[j];
            b[i] = s;
            q += s * mu[i];
        }
    }

    float lse;
    {
        float mx = pi[0];
#pragma unroll
        for (int t = 1; t < K_; ++t) mx = fmaxf(mx, pi[t]);
        float se = 0.f;
#pragma unroll
        for (int t = 0; t < K_; ++t) se += __expf(pi[t] - mx);
        lse = mx + __logf(se);
    }

    const float LOG2PI = 1.8378770664093453f;
    const float LOG2E  = 1.4426950408889634f;
    const float ALPHA  = 0.72134752044448170f;  // 0.5 * log2e
    float cst2 = ((pi[k] - lse) - 0.5f * (logdet + 8.f * LOG2PI)) * LOG2E;

    // Full-matrix V table: V[8i+j] = -alpha*A2[i][j] (UN-doubled, symmetric)
    float V[NF];
#pragma unroll
    for (int i = 0; i < D_; ++i)
#pragma unroll
        for (int j = 0; j < D_; ++j)
            V[8 * i + j] = -ALPHA * ((i >= j) ? M[i][j] : M[j][i]);
#pragma unroll
    for (int j = 0; j < D_; ++j) V[64 + j] = 2.f * ALPHA * b[j];
    V[72] = cst2 - ALPHA * q;
#pragma unroll
    for (int j = 73; j < NF; ++j) V[j] = 0.f;

    // fragment table: hot-kernel lane l reads wsV[s][l][0..7], l = h*32 + k
#pragma unroll
    for (int s = 0; s < NS; ++s)
#pragma unroll
        for (int h = 0; h < 2; ++h) {
            half8 hv;
#pragma unroll
            for (int j = 0; j < 8; ++j) hv[j] = (_Float16)V[16 * s + 8 * h + j];
            *(half8*)&wsV[(s * 64 + h * 32 + k) * 8] = hv;
        }
}

__global__ __launch_bounds__(NTHREADS) void gmm_mfma(
    const float* __restrict__ x,
    const _Float16* __restrict__ wsV,
    float* __restrict__ out)
{
    const int tid  = threadIdx.x;
    const int lane = tid & 63;
    const int m    = lane & 31;
    const bool h1  = lane >= 32;

    const int w  = blockIdx.x * (NTHREADS / 64) + (tid >> 6);
    const int t0 = w * TPW;
    const float4* xp = (const float4*)x;
    const float LN2 = 0.69314718055994531f;

    // ---- all x-loads issued first ----
    float xv[TPW][D_];
#pragma unroll
    for (int u = 0; u < TPW; ++u) {
        const int n = (t0 + u) * 32 + m;
        float4 a = xp[2 * n], b2 = xp[2 * n + 1];
        xv[u][0] = a.x;  xv[u][1] = a.y;  xv[u][2] = a.z;  xv[u][3] = a.w;
        xv[u][4] = b2.x; xv[u][5] = b2.y; xv[u][6] = b2.z; xv[u][7] = b2.w;
    }

    // A-fragments from the 5KB L2-resident table (latency hides under x-loads)
    const half8* wp = (const half8*)wsV;
    half8 wf[NS];
#pragma unroll
    for (int s = 0; s < NS; ++s) wf[s] = wp[s * 64 + lane];

    // loop-invariant constants: zero C-operand, (1,0,...,0) const fragment
    f32x16 zc;
#pragma unroll
    for (int r = 0; r < 16; ++r) zc[r] = 0.f;
    half8 c10;
#pragma unroll
    for (int j = 0; j < 8; ++j) c10[j] = (_Float16)((j == 0) ? 1.f : 0.f);

#pragma unroll
    for (int u = 0; u < TPW; ++u) {
        // row-structured fragments: slice (s,h) = row i=2s+h of x_i*x_j.
        // bc[s] = x_{2s+h} via one cndmask; products packed with cvt_pkrtz.
        half8 bq[4];
#pragma unroll
        for (int s = 0; s < 4; ++s) {
            float bc = h1 ? xv[u][2 * s + 1] : xv[u][2 * s];
#pragma unroll
            for (int jp = 0; jp < 4; ++jp) {
                fp16x2 pk = __builtin_amdgcn_cvt_pkrtz(bc * xv[u][2 * jp],
                                                       bc * xv[u][2 * jp + 1]);
                bq[s][2 * jp]     = (_Float16)pk[0];
                bq[s][2 * jp + 1] = (_Float16)pk[1];
            }
        }
        // s=4 block: h0 = linear features (packed x), h1 = (1,0,...)
        half8 xh;
#pragma unroll
        for (int jp = 0; jp < 4; ++jp) {
            fp16x2 pk = __builtin_amdgcn_cvt_pkrtz(xv[u][2 * jp], xv[u][2 * jp + 1]);
            xh[2 * jp]     = (_Float16)pk[0];
            xh[2 * jp + 1] = (_Float16)pk[1];
        }
        half8 bf4 = h1 ? c10 : xh;

        f32x16 acc;
        acc = __builtin_amdgcn_mfma_f32_32x32x16_f16(wf[0], bq[0], zc,  0, 0, 0);
        acc = __builtin_amdgcn_mfma_f32_32x32x16_f16(wf[1], bq[1], acc, 0, 0, 0);
        acc = __builtin_amdgcn_mfma_f32_32x32x16_f16(wf[2], bq[2], acc, 0, 0, 0);
        acc = __builtin_amdgcn_mfma_f32_32x32x16_f16(wf[3], bq[3], acc, 0, 0, 0);
        acc = __builtin_amdgcn_mfma_f32_32x32x16_f16(wf[4], bf4,   acc, 0, 0, 0);

        // k-reduce: 16 exp2 + pairwise tree + cross-half shfl
        float e0 = exp2f(acc[0]),  e1 = exp2f(acc[1]),  e2 = exp2f(acc[2]),  e3 = exp2f(acc[3]);
        float e4 = exp2f(acc[4]),  e5 = exp2f(acc[5]),  e6 = exp2f(acc[6]),  e7 = exp2f(acc[7]);
        float e8 = exp2f(acc[8]),  e9 = exp2f(acc[9]),  ea = exp2f(acc[10]), eb = exp2f(acc[11]);
        float ec = exp2f(acc[12]), ed = exp2f(acc[13]), ee = exp2f(acc[14]), ef = exp2f(acc[15]);
        float s0 = (e0 + e1) + (e2 + e3);
        float s1 = (e4 + e5) + (e6 + e7);
        float s2 = (e8 + e9) + (ea + eb);
        float s3 = (ec + ed) + (ee + ef);
        float tot = (s0 + s1) + (s2 + s3);
        tot += __shfl_xor(tot, 32, 64);
        float res = log2f(tot) * LN2;
        if (!h1) out[(t0 + u) * 32 + m] = res;  // coalesced 128B store
    }
}

extern "C" void kernel_launch(void* const* d_in, const int* in_sizes, int n_in,
                              void* d_out, int out_size, void* d_ws, size_t ws_size,
                              hipStream_t stream) {
    const float* x     = (const float*)d_in[0];
    const float* pi    = (const float*)d_in[1];
    const float* means = (const float*)d_in[2];
    const float* chol  = (const float*)d_in[3];
    float* out = (float*)d_out;
    _Float16* wsV = (_Float16*)d_ws;
    (void)in_sizes; (void)n_in; (void)out_size; (void)ws_size;

    gmm_prep<<<1, 64, 0, stream>>>(pi, means, chol, wsV);
    gmm_mfma<<<NBLOCKS, NTHREADS, 0, stream>>>(x, wsV, out);
}